// Round 1
// 559.297 us; speedup vs baseline: 1.0564x; 1.0564x over previous
//
#include <hip/hip_runtime.h>
#include <cstdint>

// out = sigmoid(X @ W + b)
// X: (8192 x 4096) fp32 (detected), W: (4096 x 4096) fp32 K x N, b: (4096).
// Pipeline: prep (X->bf16, W->WT bf16 transposed) then bf16 MFMA GEMM.
// MODE 0 GEMM: 256x256 tile, BK=64, 8 waves, 128KB double-buffered LDS,
// 4-phase-per-K-tile schedule with counted s_waitcnt vmcnt(6) (3 half-tiles
// always in flight across barriers), XOR-swizzled LDS (0 bank conflicts),
// setprio(1) around MFMA clusters, XCD-aware block swizzle.
#define MDIM 8192
#define NDIM 4096
#define KDIM 4096
#define NT (KDIM / 64)  // 64 K-tiles of BK=64

typedef __bf16 bf16x8 __attribute__((ext_vector_type(8)));
typedef float f32x4 __attribute__((ext_vector_type(4)));

#define MFMA16 __builtin_amdgcn_mfma_f32_16x16x32_bf16

__device__ __forceinline__ void gload_lds16(const void* g, void* l) {
    // async global->LDS, 16B/lane; LDS dest = wave-uniform base + lane*16
    __builtin_amdgcn_global_load_lds(
        (const __attribute__((address_space(1))) uint32_t*)g,
        (__attribute__((address_space(3))) uint32_t*)l, 16, 0, 0);
}

__device__ __forceinline__ unsigned short bf16_bits(float f) {
    __bf16 b = (__bf16)f;
    return __builtin_bit_cast(unsigned short, b);
}

// Called by ALL threads (uses __syncthreads_and). 1 if fp32, 0 if bf16.
__device__ __forceinline__ int detect_f32(const void* X) {
    int ok = 1;
    if (threadIdx.x < 128) {
        unsigned short h = ((const unsigned short*)X)[threadIdx.x];
        ok = (h <= 0x3F80);
    }
    return __syncthreads_and(ok) ? 0 : 1;
}

// ---------------- prep: X fp32->bf16 AND W (KxN) -> WT (NxK) bf16 ----------
__global__ __launch_bounds__(256) void prep(const void* __restrict__ X,
                                            const void* __restrict__ W,
                                            __bf16* __restrict__ Xb,
                                            __bf16* __restrict__ WT) {
    const int f32 = detect_f32(X);
    const int t = threadIdx.x;
    if (blockIdx.x < 8192) {
        if (!f32) return;  // bf16 mode: GEMM reads X directly
        const float* Xf = (const float*)X;
        const long base = ((long)blockIdx.x * 256 + t) * 16;
#pragma unroll
        for (int c = 0; c < 2; ++c) {
            float4 v0 = *(const float4*)(Xf + base + c * 8);
            float4 v1 = *(const float4*)(Xf + base + c * 8 + 4);
            unsigned short r[8] = {bf16_bits(v0.x), bf16_bits(v0.y),
                                   bf16_bits(v0.z), bf16_bits(v0.w),
                                   bf16_bits(v1.x), bf16_bits(v1.y),
                                   bf16_bits(v1.z), bf16_bits(v1.w)};
            *(uint4*)(Xb + base + c * 8) = *(const uint4*)r;
        }
        return;
    }
    __shared__ unsigned short tile[64 * 65];
    const int bid = blockIdx.x - 8192;
    const int n0 = (bid & 63) * 64;
    const int k0 = (bid >> 6) * 64;
    if (f32) {
        const float* Wf = (const float*)W;
#pragma unroll
        for (int p = 0; p < 4; ++p) {
            const int ch = p * 256 + t;
            const int kr = ch >> 4;
            const int nc = ch & 15;
            float4 v = *(const float4*)(Wf + (long)(k0 + kr) * NDIM + n0 + nc * 4);
            tile[(nc * 4 + 0) * 65 + kr] = bf16_bits(v.x);
            tile[(nc * 4 + 1) * 65 + kr] = bf16_bits(v.y);
            tile[(nc * 4 + 2) * 65 + kr] = bf16_bits(v.z);
            tile[(nc * 4 + 3) * 65 + kr] = bf16_bits(v.w);
        }
    } else {
        const __bf16* Wb = (const __bf16*)W;
#pragma unroll
        for (int p = 0; p < 2; ++p) {
            const int ch = p * 256 + t;
            const int kr = ch >> 3;
            const int nc = ch & 7;
            uint4 v = *(const uint4*)(Wb + (long)(k0 + kr) * NDIM + n0 + nc * 8);
            const unsigned short* e = (const unsigned short*)&v;
#pragma unroll
            for (int i = 0; i < 8; ++i) tile[(nc * 8 + i) * 65 + kr] = e[i];
        }
    }
    __syncthreads();
#pragma unroll
    for (int p = 0; p < 2; ++p) {
        const int ch = p * 256 + t;
        const int nr = ch >> 3;
        const int kc = ch & 7;
        unsigned short r[8];
#pragma unroll
        for (int i = 0; i < 8; ++i) r[i] = tile[nr * 65 + kc * 8 + i];
        *(uint4*)(WT + (long)(n0 + nr) * KDIM + k0 + kc * 8) = *(uint4*)r;
    }
}

// stand-alone transpose for MODE 1 (no Xb workspace)
__global__ __launch_bounds__(256) void transpose_w(const void* __restrict__ X,
                                                   const void* __restrict__ W,
                                                   __bf16* __restrict__ WT) {
    __shared__ unsigned short tile[64 * 65];
    const int f32 = detect_f32(X);
    const int t = threadIdx.x;
    const int k0 = blockIdx.y * 64;
    const int n0 = blockIdx.x * 64;
    if (f32) {
        const float* Wf = (const float*)W;
#pragma unroll
        for (int p = 0; p < 4; ++p) {
            const int ch = p * 256 + t;
            const int kr = ch >> 4;
            const int nc = ch & 15;
            float4 v = *(const float4*)(Wf + (long)(k0 + kr) * NDIM + n0 + nc * 4);
            tile[(nc * 4 + 0) * 65 + kr] = bf16_bits(v.x);
            tile[(nc * 4 + 1) * 65 + kr] = bf16_bits(v.y);
            tile[(nc * 4 + 2) * 65 + kr] = bf16_bits(v.z);
            tile[(nc * 4 + 3) * 65 + kr] = bf16_bits(v.w);
        }
    } else {
        const __bf16* Wb = (const __bf16*)W;
#pragma unroll
        for (int p = 0; p < 2; ++p) {
            const int ch = p * 256 + t;
            const int kr = ch >> 3;
            const int nc = ch & 7;
            uint4 v = *(const uint4*)(Wb + (long)(k0 + kr) * NDIM + n0 + nc * 8);
            const unsigned short* e = (const unsigned short*)&v;
#pragma unroll
            for (int i = 0; i < 8; ++i) tile[(nc * 8 + i) * 65 + kr] = e[i];
        }
    }
    __syncthreads();
#pragma unroll
    for (int p = 0; p < 2; ++p) {
        const int ch = p * 256 + t;
        const int nr = ch >> 3;
        const int kc = ch & 7;
        unsigned short r[8];
#pragma unroll
        for (int i = 0; i < 8; ++i) r[i] = tile[nr * 65 + kc * 8 + i];
        *(uint4*)(WT + (long)(n0 + nr) * KDIM + k0 + kc * 8) = *(uint4*)r;
    }
}

// ---------------- MODE 0: 256x256 tile, 8-wave, 4-phase/K-tile GEMM --------
// Phase template (per K-tile tt, buffer db = tt&1):
//   phi1: ds_read all B frags + A half0 | stage B[tt+1] h1 | bar | lgkm0 |
//         16 MFMA (q1: m-half0 x n-half0) | bar
//   phi2: stage B[tt+2] h0 | bar | lgkm0 | q2: m-half0 x n-half1 | bar
//   phi3: ds_read A half1 (reuses A regs) | bar | lgkm0 | q3: m-half1 x n-half1 | bar
//   phi4: stage A[tt+2] h0+h1 | bar | lgkm0 | q4: m-half1 x n-half0 |
//         s_waitcnt vmcnt(6) | bar
// Race-freedom: a region's replacement loads are ISSUED only in a phase after
// its reads completed (per-phase lgkmcnt(0) before closing barrier); vmcnt(6)
// at phi4 forces tile tt+1's 8 loads landed (exactly the 6 loads of phi2+phi4
// of this tile remain in flight). Loads never drain to 0 in the main loop.
#define P_OPEN()                                        \
    do {                                                \
        __builtin_amdgcn_sched_barrier(0);              \
        __builtin_amdgcn_s_barrier();                   \
        asm volatile("s_waitcnt lgkmcnt(0)" ::: "memory"); \
        __builtin_amdgcn_sched_barrier(0);              \
    } while (0)
#define P_CLOSE()                          \
    do {                                   \
        __builtin_amdgcn_sched_barrier(0); \
        __builtin_amdgcn_s_barrier();      \
    } while (0)

__global__ __launch_bounds__(512, 2) void gemm256(
    const void* __restrict__ X, const __bf16* __restrict__ Xb,
    const __bf16* __restrict__ WT, const void* __restrict__ bias,
    void* __restrict__ out) {
    __shared__ __bf16 sA[2][256][64];  // 64 KB (double-buffered A tile)
    __shared__ __bf16 sB[2][256][64];  // 64 KB
    const int f32 = detect_f32(X);
    const __bf16* __restrict__ Abf = f32 ? Xb : (const __bf16*)X;
    const int t = threadIdx.x;
    const int lane = t & 63;
    const int wid = t >> 6;   // 0..7
    const int wm = wid >> 2;  // 0..1  (wave's 128-row half)
    const int wn = wid & 3;   // 0..3  (wave's 64-col block)
    const int lrow = lane & 15;
    const int quad = lane >> 4;
    const int l7 = lrow & 7;

    // bijective XCD swizzle (512 wgs % 8 == 0): 64 consecutive tiles per XCD
    const int flat = blockIdx.x;
    const int swz = (flat & 7) * (512 / 8) + (flat >> 3);
    const long m0 = (long)(swz >> 4) * 256;  // 32 row tiles
    const long n0 = (long)(swz & 15) * 256;  // 16 col tiles

    // staging: lane = r8*8+c8 fetches global chunk (c8^r8) of row r8; LDS
    // stays glds-linear so slot s of row r holds chunk s^(r&7) (proven swizzle)
    const int r8 = lane >> 3;
    const int c8 = lane & 7;
    const int cs = (c8 ^ r8) * 8;
    const __bf16* gA = Abf + (m0 + wid * 8 + r8) * KDIM + cs;
    const __bf16* gB = WT + (n0 + wid * 8 + r8) * KDIM + cs;
    __bf16* lA = &sA[0][wid * 8][0];  // wave-uniform LDS bases
    __bf16* lB = &sB[0][wid * 8][0];

    auto stage_a = [&](int tt2) {  // both 128-row halves (4 glds/thread)
        const long off = (long)(tt2 & 1) * 16384;
        const long ko = (long)(tt2 & (NT - 1)) * 64;
        gload_lds16(gA + ko, lA + off);
        gload_lds16(gA + (long)64 * KDIM + ko, lA + off + 4096);
        gload_lds16(gA + (long)128 * KDIM + ko, lA + off + 8192);
        gload_lds16(gA + (long)192 * KDIM + ko, lA + off + 12288);
    };
    auto stage_b = [&](int tt2, int h) {  // one 128-row half (2 glds/thread)
        const long off = (long)(tt2 & 1) * 16384 + (long)h * 8192;
        const long ko = (long)(tt2 & (NT - 1)) * 64;
        gload_lds16(gB + (long)(h * 128) * KDIM + ko, lB + off);
        gload_lds16(gB + (long)(h * 128 + 64) * KDIM + ko, lB + off + 4096);
    };

    // per-lane swizzled fragment offsets (k-chunk ks*4+quad, slot ^= lrow&7)
    const int soff0 = (quad ^ l7) * 8;
    const int soff1 = ((4 + quad) ^ l7) * 8;
    const __bf16* pa = &sA[0][wm * 128 + lrow][0];
    const __bf16* pb = &sB[0][wn * 64 + lrow][0];

    f32x4 acc[8][4] = {};

    // prologue: tile0 fully (8 loads), then tile1 {Bh0, Ah0+h1} (6 loads);
    // vmcnt(6) -> tile0 landed, tile1's 6 stay in flight (steady state).
    stage_a(0);
    stage_b(0, 0);
    stage_b(0, 1);
    stage_b(1, 0);
    stage_a(1);
    __builtin_amdgcn_sched_barrier(0);
    asm volatile("s_waitcnt vmcnt(6)" ::: "memory");
    __builtin_amdgcn_sched_barrier(0);
    __builtin_amdgcn_s_barrier();

#pragma unroll 1
    for (int tt = 0; tt < NT; ++tt) {
        const int db = tt & 1;
        const __bf16* paT = pa + db * 16384;
        const __bf16* pbT = pb + db * 16384;
        bf16x8 aF[4][2], bF[4][2];
        // ---- phase 1: read all B + A-half0; stage B[tt+1]h1; q1 ----
#pragma unroll
        for (int j = 0; j < 4; ++j) {
            bF[j][0] = *(const bf16x8*)(pbT + j * 1024 + soff0);
            bF[j][1] = *(const bf16x8*)(pbT + j * 1024 + soff1);
        }
#pragma unroll
        for (int i = 0; i < 4; ++i) {
            aF[i][0] = *(const bf16x8*)(paT + i * 1024 + soff0);
            aF[i][1] = *(const bf16x8*)(paT + i * 1024 + soff1);
        }
        stage_b(tt + 1, 1);
        P_OPEN();
        __builtin_amdgcn_s_setprio(1);
#pragma unroll
        for (int i = 0; i < 4; ++i)
#pragma unroll
            for (int j = 0; j < 2; ++j) {
                acc[i][j] = MFMA16(aF[i][0], bF[j][0], acc[i][j], 0, 0, 0);
                acc[i][j] = MFMA16(aF[i][1], bF[j][1], acc[i][j], 0, 0, 0);
            }
        __builtin_amdgcn_s_setprio(0);
        P_CLOSE();
        // ---- phase 2: stage B[tt+2]h0; q2 ----
        stage_b(tt + 2, 0);
        P_OPEN();
        __builtin_amdgcn_s_setprio(1);
#pragma unroll
        for (int i = 0; i < 4; ++i)
#pragma unroll
            for (int j = 2; j < 4; ++j) {
                acc[i][j] = MFMA16(aF[i][0], bF[j][0], acc[i][j], 0, 0, 0);
                acc[i][j] = MFMA16(aF[i][1], bF[j][1], acc[i][j], 0, 0, 0);
            }
        __builtin_amdgcn_s_setprio(0);
        P_CLOSE();
        // ---- phase 3: read A-half1 (reuse aF regs); q3 ----
#pragma unroll
        for (int i = 0; i < 4; ++i) {
            aF[i][0] = *(const bf16x8*)(paT + 4096 + i * 1024 + soff0);
            aF[i][1] = *(const bf16x8*)(paT + 4096 + i * 1024 + soff1);
        }
        P_OPEN();
        __builtin_amdgcn_s_setprio(1);
#pragma unroll
        for (int i = 0; i < 4; ++i)
#pragma unroll
            for (int j = 2; j < 4; ++j) {
                acc[i + 4][j] = MFMA16(aF[i][0], bF[j][0], acc[i + 4][j], 0, 0, 0);
                acc[i + 4][j] = MFMA16(aF[i][1], bF[j][1], acc[i + 4][j], 0, 0, 0);
            }
        __builtin_amdgcn_s_setprio(0);
        P_CLOSE();
        // ---- phase 4: stage A[tt+2] h0+h1; q4; counted vmcnt(6) ----
        stage_a(tt + 2);
        P_OPEN();
        __builtin_amdgcn_s_setprio(1);
#pragma unroll
        for (int i = 0; i < 4; ++i)
#pragma unroll
            for (int j = 0; j < 2; ++j) {
                acc[i + 4][j] = MFMA16(aF[i][0], bF[j][0], acc[i + 4][j], 0, 0, 0);
                acc[i + 4][j] = MFMA16(aF[i][1], bF[j][1], acc[i + 4][j], 0, 0, 0);
            }
        __builtin_amdgcn_s_setprio(0);
        __builtin_amdgcn_sched_barrier(0);
        asm volatile("s_waitcnt vmcnt(6)" ::: "memory");
        __builtin_amdgcn_sched_barrier(0);
        __builtin_amdgcn_s_barrier();
    }

    // epilogue: C/D layout col=lane&15, row=quad*4+reg
    const int crow0 = (int)m0 + wm * 128 + quad * 4;
    if (f32) {
        float* of = (float*)out;
        const float* bf = (const float*)bias;
#pragma unroll
        for (int j = 0; j < 4; ++j) {
            const int col = (int)n0 + wn * 64 + j * 16 + lrow;
            const float bv = bf[col];
#pragma unroll
            for (int i = 0; i < 8; ++i) {
                const long rbase = (long)(crow0 + i * 16) * NDIM + col;
#pragma unroll
                for (int r = 0; r < 4; ++r) {
                    const float x = acc[i][j][r] + bv;
                    of[rbase + (long)r * NDIM] = 1.0f / (1.0f + __expf(-x));
                }
            }
        }
    } else {
        __bf16* ob = (__bf16*)out;
        const __bf16* bb = (const __bf16*)bias;
#pragma unroll
        for (int j = 0; j < 4; ++j) {
            const int col = (int)n0 + wn * 64 + j * 16 + lrow;
            const float bv = (float)bb[col];
#pragma unroll
            for (int i = 0; i < 8; ++i) {
                const long rbase = (long)(crow0 + i * 16) * NDIM + col;
#pragma unroll
                for (int r = 0; r < 4; ++r) {
                    const float x = acc[i][j][r] + bv;
                    ob[rbase + (long)r * NDIM] = (__bf16)(1.0f / (1.0f + __expf(-x)));
                }
            }
        }
    }
}

// ---------------- verified BK=32 fallbacks (MODE 1/2), unchanged ----------
template <int MODE>
__global__ __launch_bounds__(256) void gemm_bias_sigmoid(
    const void* __restrict__ X, const __bf16* __restrict__ Xb,
    const void* __restrict__ Wp, const __bf16* __restrict__ WT,
    const void* __restrict__ bias, void* __restrict__ out) {
    __shared__ __bf16 sA[128 * 64];
    __shared__ __bf16 sB[128 * 64];
    const int f32 = detect_f32(X);
    const int t = threadIdx.x;
    const int lane = t & 63;
    const int wid = t >> 6;
    const int m0 = blockIdx.y * 128;
    const int n0 = blockIdx.x * 128;
    const int wm = (wid & 1) * 64;
    const int wn = (wid >> 1) * 64;
    const int lrow = lane & 15;
    const int quad = lane >> 4;

    f32x4 acc[4][4] = {};

    {
        // ---- BK=32 fallback paths ----
        const int srow = t >> 2;
        const int schk = t & 3;
        __bf16* ldsA = sA + wid * 512;
        __bf16* ldsB = sB + wid * 512;
        const int arow = t >> 1;
        const int acol = (t & 1) * 16;
        const int fp = t & 15;
        const int fc = t >> 4;
        uint32_t* sB32 = (uint32_t*)sB;

        auto compute = [&]() {
            bf16x8 aF[4], bFr[4];
            const __bf16* pa = sA + (wm + lrow) * 32 + quad * 8;
            const __bf16* pb = sB + (wn + lrow) * 32 + quad * 8;
#pragma unroll
            for (int i = 0; i < 4; ++i) aF[i] = *(const bf16x8*)(pa + i * 512);
#pragma unroll
            for (int j = 0; j < 4; ++j) bFr[j] = *(const bf16x8*)(pb + j * 512);
#pragma unroll
            for (int i = 0; i < 4; ++i)
#pragma unroll
                for (int j = 0; j < 4; ++j)
                    acc[i][j] = MFMA16(aF[i], bFr[j], acc[i][j], 0, 0, 0);
        };

        if (MODE == 1 && !f32) {
            const __bf16* gA = (const __bf16*)X + (long)(m0 + srow) * KDIM + schk * 8;
            const __bf16* gB = WT + (long)(n0 + srow) * KDIM + schk * 8;
            for (int kt = 0; kt < KDIM / 32; ++kt) {
                const __bf16* a0 = gA + kt * 32;
                gload_lds16(a0, ldsA);
                gload_lds16(a0 + (long)64 * KDIM, ldsA + 2048);
                const __bf16* b0 = gB + kt * 32;
                gload_lds16(b0, ldsB);
                gload_lds16(b0 + (long)64 * KDIM, ldsB + 2048);
                __syncthreads();
                compute();
                __syncthreads();
            }
        } else if (MODE == 1) {
            const float* Xf = (const float*)X;
            const __bf16* gB = WT + (long)(n0 + srow) * KDIM + schk * 8;
            for (int kt = 0; kt < KDIM / 32; ++kt) {
                const __bf16* b0 = gB + kt * 32;
                gload_lds16(b0, ldsB);
                gload_lds16(b0 + (long)64 * KDIM, ldsB + 2048);
                const float* ap = Xf + (long)(m0 + arow) * KDIM + kt * 32 + acol;
                float4 v0 = *(const float4*)(ap);
                float4 v1 = *(const float4*)(ap + 4);
                float4 v2 = *(const float4*)(ap + 8);
                float4 v3 = *(const float4*)(ap + 12);
                unsigned short r[16] = {
                    bf16_bits(v0.x), bf16_bits(v0.y), bf16_bits(v0.z), bf16_bits(v0.w),
                    bf16_bits(v1.x), bf16_bits(v1.y), bf16_bits(v1.z), bf16_bits(v1.w),
                    bf16_bits(v2.x), bf16_bits(v2.y), bf16_bits(v2.z), bf16_bits(v2.w),
                    bf16_bits(v3.x), bf16_bits(v3.y), bf16_bits(v3.z), bf16_bits(v3.w)};
                *(uint4*)(sA + arow * 32 + acol) = *(const uint4*)(r);
                *(uint4*)(sA + arow * 32 + acol + 8) = *(const uint4*)(r + 8);
                __syncthreads();
                compute();
                __syncthreads();
            }
        } else if (MODE == 2 && !f32) {
            const __bf16* gA = (const __bf16*)X + (long)(m0 + srow) * KDIM + schk * 8;
            const __bf16* Wb = (const __bf16*)Wp;
            for (int kt = 0; kt < KDIM / 32; ++kt) {
                const __bf16* a0 = gA + kt * 32;
                gload_lds16(a0, ldsA);
                gload_lds16(a0 + (long)64 * KDIM, ldsA + 2048);
                const __bf16* w0 = Wb + (long)(kt * 32 + 2 * fp) * NDIM + n0 + fc * 8;
                uint4 g0 = *(const uint4*)(w0);
                uint4 g1 = *(const uint4*)(w0 + NDIM);
                const unsigned short* e0 = (const unsigned short*)&g0;
                const unsigned short* e1 = (const unsigned short*)&g1;
#pragma unroll
                for (int i = 0; i < 8; ++i)
                    sB32[(fc * 8 + i) * 16 + fp] =
                        (uint32_t)e0[i] | ((uint32_t)e1[i] << 16);
                __syncthreads();
                compute();
                __syncthreads();
            }
        } else if (MODE == 2) {
            const float* Xf = (const float*)X;
            const float* Wf = (const float*)Wp;
            for (int kt = 0; kt < KDIM / 32; ++kt) {
                const float* ap = Xf + (long)(m0 + arow) * KDIM + kt * 32 + acol;
                float4 v0 = *(const float4*)(ap);
                float4 v1 = *(const float4*)(ap + 4);
                float4 v2 = *(const float4*)(ap + 8);
                float4 v3 = *(const float4*)(ap + 12);
                unsigned short r[16] = {
                    bf16_bits(v0.x), bf16_bits(v0.y), bf16_bits(v0.z), bf16_bits(v0.w),
                    bf16_bits(v1.x), bf16_bits(v1.y), bf16_bits(v1.z), bf16_bits(v1.w),
                    bf16_bits(v2.x), bf16_bits(v2.y), bf16_bits(v2.z), bf16_bits(v2.w),
                    bf16_bits(v3.x), bf16_bits(v3.y), bf16_bits(v3.z), bf16_bits(v3.w)};
                *(uint4*)(sA + arow * 32 + acol) = *(const uint4*)(r);
                *(uint4*)(sA + arow * 32 + acol + 8) = *(const uint4*)(r + 8);
                const float* w0 = Wf + (long)(kt * 32 + 2 * fp) * NDIM + n0 + fc * 8;
                float4 u0 = *(const float4*)(w0);
                float4 u1 = *(const float4*)(w0 + 4);
                float4 u2 = *(const float4*)(w0 + NDIM);
                float4 u3 = *(const float4*)(w0 + NDIM + 4);
                float k0v[8] = {u0.x, u0.y, u0.z, u0.w, u1.x, u1.y, u1.z, u1.w};
                float k1v[8] = {u2.x, u2.y, u2.z, u2.w, u3.x, u3.y, u3.z, u3.w};
#pragma unroll
                for (int i = 0; i < 8; ++i)
                    sB32[(fc * 8 + i) * 16 + fp] =
                        (uint32_t)bf16_bits(k0v[i]) |
                        ((uint32_t)bf16_bits(k1v[i]) << 16);
                __syncthreads();
                compute();
                __syncthreads();
            }
        }
    }

    // epilogue: C/D layout col=lane&15, row=quad*4+reg
    const int crow = m0 + wm + quad * 4;
    if (f32) {
        float* of = (float*)out;
        const float* bf = (const float*)bias;
#pragma unroll
        for (int j = 0; j < 4; ++j) {
            const int col = n0 + wn + j * 16 + lrow;
            const float bv = bf[col];
#pragma unroll
            for (int i = 0; i < 4; ++i) {
                const long rbase = (long)(crow + i * 16) * NDIM + col;
#pragma unroll
                for (int r = 0; r < 4; ++r) {
                    const float x = acc[i][j][r] + bv;
                    of[rbase + (long)r * NDIM] = 1.0f / (1.0f + __expf(-x));
                }
            }
        }
    } else {
        __bf16* ob = (__bf16*)out;
        const __bf16* bb = (const __bf16*)bias;
#pragma unroll
        for (int j = 0; j < 4; ++j) {
            const int col = n0 + wn + j * 16 + lrow;
            const float bv = (float)bb[col];
#pragma unroll
            for (int i = 0; i < 4; ++i) {
                const long rbase = (long)(crow + i * 16) * NDIM + col;
#pragma unroll
                for (int r = 0; r < 4; ++r) {
                    const float x = acc[i][j][r] + bv;
                    ob[rbase + (long)r * NDIM] = (__bf16)(1.0f / (1.0f + __expf(-x)));
                }
            }
        }
    }
}

extern "C" void kernel_launch(void* const* d_in, const int* in_sizes, int n_in,
                              void* d_out, int out_size, void* d_ws,
                              size_t ws_size, hipStream_t stream) {
    const void* X = d_in[0];     // input_data (8192 x 4096)
    const void* W = d_in[1];     // W (4096 x 4096), K x N
    const void* bias = d_in[2];  // hidden_bias (4096)

    const size_t wt_bytes = (size_t)KDIM * NDIM * sizeof(__bf16);  // 33.5 MB
    const size_t xb_bytes = (size_t)MDIM * KDIM * sizeof(__bf16);  // 67 MB

    if (ws_size >= wt_bytes + xb_bytes) {
        __bf16* WT = (__bf16*)d_ws;
        __bf16* Xb = (__bf16*)((char*)d_ws + wt_bytes);
        prep<<<8192 + 4096, 256, 0, stream>>>(X, W, Xb, WT);
        gemm256<<<dim3((MDIM / 256) * (NDIM / 256)), 512, 0, stream>>>(
            X, Xb, WT, bias, d_out);
    } else if (ws_size >= wt_bytes) {
        __bf16* WT = (__bf16*)d_ws;
        transpose_w<<<dim3(NDIM / 64, KDIM / 64), 256, 0, stream>>>(X, W, WT);
        dim3 gg(NDIM / 128, MDIM / 128);
        gemm_bias_sigmoid<1><<<gg, 256, 0, stream>>>(X, nullptr, W, WT, bias, d_out);
    } else {
        dim3 gg(NDIM / 128, MDIM / 128);
        gemm_bias_sigmoid<2><<<gg, 256, 0, stream>>>(X, nullptr, W, nullptr, bias, d_out);
    }
}

// Round 2
// 519.270 us; speedup vs baseline: 1.1379x; 1.0771x over previous
//
#include <hip/hip_runtime.h>
#include <cstdint>

// out = sigmoid(X @ W + b)
// X: (8192 x 4096) fp32 (detected), W: (4096 x 4096) fp32 K x N, b: (4096).
// Pipeline: prep (X->bf16, W->WT bf16 transposed) then bf16 MFMA GEMM.
// MODE 0 GEMM: 256x256 tile, BK=64, 8 waves, 128KB double-buffered LDS.
// Round-2 schedule: quadrant-walk 4-phase/K-tile (reads 12/4/8/0 per phase,
// B(nq0) frags held in regs phi1->phi4), static LDS offsets via ktile<DBOFF>,
// kk-outer MFMA (dep distance 8), stage B[t+2]@phi3 / A[t+2]@phi4 with one
// counted s_waitcnt vmcnt(8) per K-tile (8-16 glds in flight, never drained),
// XOR-swizzled LDS (0 bank conflicts), setprio(1) around MFMA clusters,
// bijective XCD block swizzle.
#define MDIM 8192
#define NDIM 4096
#define KDIM 4096
#define NT (KDIM / 64)  // 64 K-tiles of BK=64

typedef __bf16 bf16x8 __attribute__((ext_vector_type(8)));
typedef float f32x4 __attribute__((ext_vector_type(4)));

#define MFMA16 __builtin_amdgcn_mfma_f32_16x16x32_bf16

__device__ __forceinline__ void gload_lds16(const void* g, void* l) {
    // async global->LDS, 16B/lane; LDS dest = wave-uniform base + lane*16
    __builtin_amdgcn_global_load_lds(
        (const __attribute__((address_space(1))) uint32_t*)g,
        (__attribute__((address_space(3))) uint32_t*)l, 16, 0, 0);
}

__device__ __forceinline__ unsigned short bf16_bits(float f) {
    __bf16 b = (__bf16)f;
    return __builtin_bit_cast(unsigned short, b);
}

// Called by ALL threads (uses __syncthreads_and). 1 if fp32, 0 if bf16.
__device__ __forceinline__ int detect_f32(const void* X) {
    int ok = 1;
    if (threadIdx.x < 128) {
        unsigned short h = ((const unsigned short*)X)[threadIdx.x];
        ok = (h <= 0x3F80);
    }
    return __syncthreads_and(ok) ? 0 : 1;
}

// ---------------- prep: X fp32->bf16 AND W (KxN) -> WT (NxK) bf16 ----------
__global__ __launch_bounds__(256) void prep(const void* __restrict__ X,
                                            const void* __restrict__ W,
                                            __bf16* __restrict__ Xb,
                                            __bf16* __restrict__ WT) {
    const int f32 = detect_f32(X);
    const int t = threadIdx.x;
    if (blockIdx.x < 8192) {
        if (!f32) return;  // bf16 mode: GEMM reads X directly
        // lane-contiguous float4 reads / 8B bf16 writes (fully coalesced)
        const float* Xf = (const float*)X;
        const long xbase = (long)blockIdx.x * 4096;
#pragma unroll
        for (int rr = 0; rr < 4; ++rr) {
            const long idx = xbase + rr * 1024 + t * 4;
            float4 v = *(const float4*)(Xf + idx);
            unsigned short r[4] = {bf16_bits(v.x), bf16_bits(v.y),
                                   bf16_bits(v.z), bf16_bits(v.w)};
            *(uint2*)(Xb + idx) = *(const uint2*)r;
        }
        return;
    }
    __shared__ unsigned short tile[64 * 65];
    const int bid = blockIdx.x - 8192;
    const int n0 = (bid & 63) * 64;
    const int k0 = (bid >> 6) * 64;
    if (f32) {
        const float* Wf = (const float*)W;
#pragma unroll
        for (int p = 0; p < 4; ++p) {
            const int ch = p * 256 + t;
            const int kr = ch >> 4;
            const int nc = ch & 15;
            float4 v = *(const float4*)(Wf + (long)(k0 + kr) * NDIM + n0 + nc * 4);
            tile[(nc * 4 + 0) * 65 + kr] = bf16_bits(v.x);
            tile[(nc * 4 + 1) * 65 + kr] = bf16_bits(v.y);
            tile[(nc * 4 + 2) * 65 + kr] = bf16_bits(v.z);
            tile[(nc * 4 + 3) * 65 + kr] = bf16_bits(v.w);
        }
    } else {
        const __bf16* Wb = (const __bf16*)W;
#pragma unroll
        for (int p = 0; p < 2; ++p) {
            const int ch = p * 256 + t;
            const int kr = ch >> 3;
            const int nc = ch & 7;
            uint4 v = *(const uint4*)(Wb + (long)(k0 + kr) * NDIM + n0 + nc * 8);
            const unsigned short* e = (const unsigned short*)&v;
#pragma unroll
            for (int i = 0; i < 8; ++i) tile[(nc * 8 + i) * 65 + kr] = e[i];
        }
    }
    __syncthreads();
#pragma unroll
    for (int p = 0; p < 2; ++p) {
        const int ch = p * 256 + t;
        const int nr = ch >> 3;
        const int kc = ch & 7;
        unsigned short r[8];
#pragma unroll
        for (int i = 0; i < 8; ++i) r[i] = tile[nr * 65 + kc * 8 + i];
        *(uint4*)(WT + (long)(n0 + nr) * KDIM + k0 + kc * 8) = *(uint4*)r;
    }
}

// stand-alone transpose for MODE 1 (no Xb workspace)
__global__ __launch_bounds__(256) void transpose_w(const void* __restrict__ X,
                                                   const void* __restrict__ W,
                                                   __bf16* __restrict__ WT) {
    __shared__ unsigned short tile[64 * 65];
    const int f32 = detect_f32(X);
    const int t = threadIdx.x;
    const int k0 = blockIdx.y * 64;
    const int n0 = blockIdx.x * 64;
    if (f32) {
        const float* Wf = (const float*)W;
#pragma unroll
        for (int p = 0; p < 4; ++p) {
            const int ch = p * 256 + t;
            const int kr = ch >> 4;
            const int nc = ch & 15;
            float4 v = *(const float4*)(Wf + (long)(k0 + kr) * NDIM + n0 + nc * 4);
            tile[(nc * 4 + 0) * 65 + kr] = bf16_bits(v.x);
            tile[(nc * 4 + 1) * 65 + kr] = bf16_bits(v.y);
            tile[(nc * 4 + 2) * 65 + kr] = bf16_bits(v.z);
            tile[(nc * 4 + 3) * 65 + kr] = bf16_bits(v.w);
        }
    } else {
        const __bf16* Wb = (const __bf16*)W;
#pragma unroll
        for (int p = 0; p < 2; ++p) {
            const int ch = p * 256 + t;
            const int kr = ch >> 3;
            const int nc = ch & 7;
            uint4 v = *(const uint4*)(Wb + (long)(k0 + kr) * NDIM + n0 + nc * 8);
            const unsigned short* e = (const unsigned short*)&v;
#pragma unroll
            for (int i = 0; i < 8; ++i) tile[(nc * 8 + i) * 65 + kr] = e[i];
        }
    }
    __syncthreads();
#pragma unroll
    for (int p = 0; p < 2; ++p) {
        const int ch = p * 256 + t;
        const int nr = ch >> 3;
        const int kc = ch & 7;
        unsigned short r[8];
#pragma unroll
        for (int i = 0; i < 8; ++i) r[i] = tile[nr * 65 + kc * 8 + i];
        *(uint4*)(WT + (long)(n0 + nr) * KDIM + k0 + kc * 8) = *(uint4*)r;
    }
}

// ---------------- MODE 0 phase helpers ----------------
#define P_OPEN()                                           \
    do {                                                   \
        __builtin_amdgcn_sched_barrier(0);                 \
        __builtin_amdgcn_s_barrier();                      \
        asm volatile("s_waitcnt lgkmcnt(0)" ::: "memory"); \
        __builtin_amdgcn_sched_barrier(0);                 \
    } while (0)
#define P_CLOSE()                          \
    do {                                   \
        __builtin_amdgcn_sched_barrier(0); \
        __builtin_amdgcn_s_barrier();      \
    } while (0)

// One K-tile = 4 phases (quadrant walk Q1:mq0xnq0, Q2:mq0xnq1, Q3:mq1xnq1,
// Q4:mq1xnq0). Reads/phase: 12/4/8/0 (B(nq0) regs live phi1->phi4; aF
// overwritten at phi3). Stage B[t+2]@phi3, A[t+2]@phi4 into THIS buffer —
// safe: B[t] LDS reads complete before phi2-close barrier, A[t] before
// phi3-close (per-wave lgkmcnt(0) precedes each wave's MFMA & barrier).
// vmcnt(8) at phi4: tile t+1's 8 loads landed; tile t+2's 8 stay in flight.
template <int DBOFF>
__device__ __forceinline__ void ktile(const __bf16* pa, const __bf16* pb,
                                      const __bf16* gA, const __bf16* gB,
                                      __bf16* lA, __bf16* lB, long ko2,
                                      int soff0, int soff1,
                                      f32x4 (&acc)[8][4]) {
    const __bf16* paT = pa + DBOFF;
    const __bf16* pbT = pb + DBOFF;
    bf16x8 aF[4][2], bF[4][2];
    // ---- phi1: read B(nq0) 4 + A(mq0) 8; MFMA Q1 ----
#pragma unroll
    for (int j = 0; j < 2; ++j) {
        bF[j][0] = *(const bf16x8*)(pbT + j * 1024 + soff0);
        bF[j][1] = *(const bf16x8*)(pbT + j * 1024 + soff1);
    }
#pragma unroll
    for (int i = 0; i < 4; ++i) {
        aF[i][0] = *(const bf16x8*)(paT + i * 1024 + soff0);
        aF[i][1] = *(const bf16x8*)(paT + i * 1024 + soff1);
    }
    asm volatile("s_waitcnt lgkmcnt(8)" ::: "memory");  // early-drain hint
    P_OPEN();
    __builtin_amdgcn_s_setprio(1);
#pragma unroll
    for (int kk = 0; kk < 2; ++kk)
#pragma unroll
        for (int i = 0; i < 4; ++i)
#pragma unroll
            for (int j = 0; j < 2; ++j)
                acc[i][j] = MFMA16(aF[i][kk], bF[j][kk], acc[i][j], 0, 0, 0);
    __builtin_amdgcn_s_setprio(0);
    P_CLOSE();
    // ---- phi2: read B(nq1) 4; MFMA Q2 (aF reused) ----
#pragma unroll
    for (int j = 2; j < 4; ++j) {
        bF[j][0] = *(const bf16x8*)(pbT + j * 1024 + soff0);
        bF[j][1] = *(const bf16x8*)(pbT + j * 1024 + soff1);
    }
    P_OPEN();
    __builtin_amdgcn_s_setprio(1);
#pragma unroll
    for (int kk = 0; kk < 2; ++kk)
#pragma unroll
        for (int i = 0; i < 4; ++i)
#pragma unroll
            for (int j = 2; j < 4; ++j)
                acc[i][j] = MFMA16(aF[i][kk], bF[j][kk], acc[i][j], 0, 0, 0);
    __builtin_amdgcn_s_setprio(0);
    P_CLOSE();
    // ---- phi3: read A(mq1) 8 (overwrite aF); stage B[t+2]; MFMA Q3 ----
#pragma unroll
    for (int i = 0; i < 4; ++i) {
        aF[i][0] = *(const bf16x8*)(paT + (4 + i) * 1024 + soff0);
        aF[i][1] = *(const bf16x8*)(paT + (4 + i) * 1024 + soff1);
    }
    gload_lds16(gB + ko2, lB + DBOFF);
    gload_lds16(gB + (long)64 * KDIM + ko2, lB + DBOFF + 4096);
    gload_lds16(gB + (long)128 * KDIM + ko2, lB + DBOFF + 8192);
    gload_lds16(gB + (long)192 * KDIM + ko2, lB + DBOFF + 12288);
    P_OPEN();
    __builtin_amdgcn_s_setprio(1);
#pragma unroll
    for (int kk = 0; kk < 2; ++kk)
#pragma unroll
        for (int i = 0; i < 4; ++i)
#pragma unroll
            for (int j = 2; j < 4; ++j)
                acc[4 + i][j] = MFMA16(aF[i][kk], bF[j][kk], acc[4 + i][j], 0, 0, 0);
    __builtin_amdgcn_s_setprio(0);
    P_CLOSE();
    // ---- phi4: stage A[t+2]; MFMA Q4 (bF[0..1] reused); vmcnt(8) ----
    gload_lds16(gA + ko2, lA + DBOFF);
    gload_lds16(gA + (long)64 * KDIM + ko2, lA + DBOFF + 4096);
    gload_lds16(gA + (long)128 * KDIM + ko2, lA + DBOFF + 8192);
    gload_lds16(gA + (long)192 * KDIM + ko2, lA + DBOFF + 12288);
    P_OPEN();
    __builtin_amdgcn_s_setprio(1);
#pragma unroll
    for (int kk = 0; kk < 2; ++kk)
#pragma unroll
        for (int i = 0; i < 4; ++i)
#pragma unroll
            for (int j = 0; j < 2; ++j)
                acc[4 + i][j] = MFMA16(aF[i][kk], bF[j][kk], acc[4 + i][j], 0, 0, 0);
    __builtin_amdgcn_s_setprio(0);
    __builtin_amdgcn_sched_barrier(0);
    asm volatile("s_waitcnt vmcnt(8)" ::: "memory");
    __builtin_amdgcn_sched_barrier(0);
    __builtin_amdgcn_s_barrier();
}

__global__ __launch_bounds__(512, 2) void gemm256(
    const void* __restrict__ X, const __bf16* __restrict__ Xb,
    const __bf16* __restrict__ WT, const void* __restrict__ bias,
    void* __restrict__ out) {
    __shared__ __bf16 sA[2][256][64];  // 64 KB (double-buffered A tile)
    __shared__ __bf16 sB[2][256][64];  // 64 KB
    const int f32 = detect_f32(X);
    const __bf16* __restrict__ Abf = f32 ? Xb : (const __bf16*)X;
    const int t = threadIdx.x;
    const int lane = t & 63;
    const int wid = t >> 6;   // 0..7
    const int wm = wid >> 2;  // 0..1  (wave's 128-row half)
    const int wn = wid & 3;   // 0..3  (wave's 64-col block)
    const int lrow = lane & 15;
    const int quad = lane >> 4;
    const int l7 = lrow & 7;

    // bijective XCD swizzle (512 wgs % 8 == 0): 64 consecutive tiles per XCD
    const int flat = blockIdx.x;
    const int swz = (flat & 7) * (512 / 8) + (flat >> 3);
    const long m0 = (long)(swz >> 4) * 256;  // 32 row tiles
    const long n0 = (long)(swz & 15) * 256;  // 16 col tiles

    // staging: lane = r8*8+c8 fetches global chunk (c8^r8) of row r8; LDS
    // stays glds-linear so slot s of row r holds chunk s^(r&7) (proven swizzle)
    const int r8 = lane >> 3;
    const int c8 = lane & 7;
    const int cs = (c8 ^ r8) * 8;
    const __bf16* gA = Abf + (m0 + wid * 8 + r8) * KDIM + cs;
    const __bf16* gB = WT + (n0 + wid * 8 + r8) * KDIM + cs;
    __bf16* lA = &sA[0][wid * 8][0];  // wave-uniform LDS bases
    __bf16* lB = &sB[0][wid * 8][0];

    // per-lane swizzled fragment offsets (k-chunk ks*4+quad, slot ^= lrow&7)
    const int soff0 = (quad ^ l7) * 8;
    const int soff1 = ((4 + quad) ^ l7) * 8;
    const __bf16* pa = &sA[0][wm * 128 + lrow][0];
    const __bf16* pb = &sB[0][wn * 64 + lrow][0];

    f32x4 acc[8][4] = {};

    // prologue: stage tile0 (8 loads) + tile1 (8 loads); vmcnt(8) -> tile0
    // landed, tile1's 8 stay in flight (steady state).
    {
        gload_lds16(gA, lA);
        gload_lds16(gA + (long)64 * KDIM, lA + 4096);
        gload_lds16(gA + (long)128 * KDIM, lA + 8192);
        gload_lds16(gA + (long)192 * KDIM, lA + 12288);
        gload_lds16(gB, lB);
        gload_lds16(gB + (long)64 * KDIM, lB + 4096);
        gload_lds16(gB + (long)128 * KDIM, lB + 8192);
        gload_lds16(gB + (long)192 * KDIM, lB + 12288);
        gload_lds16(gA + 64, lA + 16384);
        gload_lds16(gA + (long)64 * KDIM + 64, lA + 16384 + 4096);
        gload_lds16(gA + (long)128 * KDIM + 64, lA + 16384 + 8192);
        gload_lds16(gA + (long)192 * KDIM + 64, lA + 16384 + 12288);
        gload_lds16(gB + 64, lB + 16384);
        gload_lds16(gB + (long)64 * KDIM + 64, lB + 16384 + 4096);
        gload_lds16(gB + (long)128 * KDIM + 64, lB + 16384 + 8192);
        gload_lds16(gB + (long)192 * KDIM + 64, lB + 16384 + 12288);
    }
    __builtin_amdgcn_sched_barrier(0);
    asm volatile("s_waitcnt vmcnt(8)" ::: "memory");
    __builtin_amdgcn_sched_barrier(0);
    __builtin_amdgcn_s_barrier();

#pragma unroll 1
    for (int tt = 0; tt < NT; tt += 2) {
        const long ko2a = (long)((tt + 2) & (NT - 1)) * 64;
        const long ko2b = (long)((tt + 3) & (NT - 1)) * 64;
        ktile<0>(pa, pb, gA, gB, lA, lB, ko2a, soff0, soff1, acc);
        ktile<16384>(pa, pb, gA, gB, lA, lB, ko2b, soff0, soff1, acc);
    }

    // epilogue: C/D layout col=lane&15, row=quad*4+reg
    const int crow0 = (int)m0 + wm * 128 + quad * 4;
    if (f32) {
        float* of = (float*)out;
        const float* bf = (const float*)bias;
#pragma unroll
        for (int j = 0; j < 4; ++j) {
            const int col = (int)n0 + wn * 64 + j * 16 + lrow;
            const float bv = bf[col];
#pragma unroll
            for (int i = 0; i < 8; ++i) {
                const long rbase = (long)(crow0 + i * 16) * NDIM + col;
#pragma unroll
                for (int r = 0; r < 4; ++r) {
                    const float x = acc[i][j][r] + bv;
                    of[rbase + (long)r * NDIM] = 1.0f / (1.0f + __expf(-x));
                }
            }
        }
    } else {
        __bf16* ob = (__bf16*)out;
        const __bf16* bb = (const __bf16*)bias;
#pragma unroll
        for (int j = 0; j < 4; ++j) {
            const int col = (int)n0 + wn * 64 + j * 16 + lrow;
            const float bv = (float)bb[col];
#pragma unroll
            for (int i = 0; i < 8; ++i) {
                const long rbase = (long)(crow0 + i * 16) * NDIM + col;
#pragma unroll
                for (int r = 0; r < 4; ++r) {
                    const float x = acc[i][j][r] + bv;
                    ob[rbase + (long)r * NDIM] = (__bf16)(1.0f / (1.0f + __expf(-x)));
                }
            }
        }
    }
}

// ---------------- verified BK=32 fallbacks (MODE 1/2), unchanged ----------
template <int MODE>
__global__ __launch_bounds__(256) void gemm_bias_sigmoid(
    const void* __restrict__ X, const __bf16* __restrict__ Xb,
    const void* __restrict__ Wp, const __bf16* __restrict__ WT,
    const void* __restrict__ bias, void* __restrict__ out) {
    __shared__ __bf16 sA[128 * 64];
    __shared__ __bf16 sB[128 * 64];
    const int f32 = detect_f32(X);
    const int t = threadIdx.x;
    const int lane = t & 63;
    const int wid = t >> 6;
    const int m0 = blockIdx.y * 128;
    const int n0 = blockIdx.x * 128;
    const int wm = (wid & 1) * 64;
    const int wn = (wid >> 1) * 64;
    const int lrow = lane & 15;
    const int quad = lane >> 4;

    f32x4 acc[4][4] = {};

    {
        const int srow = t >> 2;
        const int schk = t & 3;
        __bf16* ldsA = sA + wid * 512;
        __bf16* ldsB = sB + wid * 512;
        const int arow = t >> 1;
        const int acol = (t & 1) * 16;
        const int fp = t & 15;
        const int fc = t >> 4;
        uint32_t* sB32 = (uint32_t*)sB;

        auto compute = [&]() {
            bf16x8 aF[4], bFr[4];
            const __bf16* pa = sA + (wm + lrow) * 32 + quad * 8;
            const __bf16* pb = sB + (wn + lrow) * 32 + quad * 8;
#pragma unroll
            for (int i = 0; i < 4; ++i) aF[i] = *(const bf16x8*)(pa + i * 512);
#pragma unroll
            for (int j = 0; j < 4; ++j) bFr[j] = *(const bf16x8*)(pb + j * 512);
#pragma unroll
            for (int i = 0; i < 4; ++i)
#pragma unroll
                for (int j = 0; j < 4; ++j)
                    acc[i][j] = MFMA16(aF[i], bFr[j], acc[i][j], 0, 0, 0);
        };

        if (MODE == 1 && !f32) {
            const __bf16* gA = (const __bf16*)X + (long)(m0 + srow) * KDIM + schk * 8;
            const __bf16* gB = WT + (long)(n0 + srow) * KDIM + schk * 8;
            for (int kt = 0; kt < KDIM / 32; ++kt) {
                const __bf16* a0 = gA + kt * 32;
                gload_lds16(a0, ldsA);
                gload_lds16(a0 + (long)64 * KDIM, ldsA + 2048);
                const __bf16* b0 = gB + kt * 32;
                gload_lds16(b0, ldsB);
                gload_lds16(b0 + (long)64 * KDIM, ldsB + 2048);
                __syncthreads();
                compute();
                __syncthreads();
            }
        } else if (MODE == 1) {
            const float* Xf = (const float*)X;
            const __bf16* gB = WT + (long)(n0 + srow) * KDIM + schk * 8;
            for (int kt = 0; kt < KDIM / 32; ++kt) {
                const __bf16* b0 = gB + kt * 32;
                gload_lds16(b0, ldsB);
                gload_lds16(b0 + (long)64 * KDIM, ldsB + 2048);
                const float* ap = Xf + (long)(m0 + arow) * KDIM + kt * 32 + acol;
                float4 v0 = *(const float4*)(ap);
                float4 v1 = *(const float4*)(ap + 4);
                float4 v2 = *(const float4*)(ap + 8);
                float4 v3 = *(const float4*)(ap + 12);
                unsigned short r[16] = {
                    bf16_bits(v0.x), bf16_bits(v0.y), bf16_bits(v0.z), bf16_bits(v0.w),
                    bf16_bits(v1.x), bf16_bits(v1.y), bf16_bits(v1.z), bf16_bits(v1.w),
                    bf16_bits(v2.x), bf16_bits(v2.y), bf16_bits(v2.z), bf16_bits(v2.w),
                    bf16_bits(v3.x), bf16_bits(v3.y), bf16_bits(v3.z), bf16_bits(v3.w)};
                *(uint4*)(sA + arow * 32 + acol) = *(const uint4*)(r);
                *(uint4*)(sA + arow * 32 + acol + 8) = *(const uint4*)(r + 8);
                __syncthreads();
                compute();
                __syncthreads();
            }
        } else if (MODE == 2 && !f32) {
            const __bf16* gA = (const __bf16*)X + (long)(m0 + srow) * KDIM + schk * 8;
            const __bf16* Wb = (const __bf16*)Wp;
            for (int kt = 0; kt < KDIM / 32; ++kt) {
                const __bf16* a0 = gA + kt * 32;
                gload_lds16(a0, ldsA);
                gload_lds16(a0 + (long)64 * KDIM, ldsA + 2048);
                const __bf16* w0 = Wb + (long)(kt * 32 + 2 * fp) * NDIM + n0 + fc * 8;
                uint4 g0 = *(const uint4*)(w0);
                uint4 g1 = *(const uint4*)(w0 + NDIM);
                const unsigned short* e0 = (const unsigned short*)&g0;
                const unsigned short* e1 = (const unsigned short*)&g1;
#pragma unroll
                for (int i = 0; i < 8; ++i)
                    sB32[(fc * 8 + i) * 16 + fp] =
                        (uint32_t)e0[i] | ((uint32_t)e1[i] << 16);
                __syncthreads();
                compute();
                __syncthreads();
            }
        } else if (MODE == 2) {
            const float* Xf = (const float*)X;
            const float* Wf = (const float*)Wp;
            for (int kt = 0; kt < KDIM / 32; ++kt) {
                const float* ap = Xf + (long)(m0 + arow) * KDIM + kt * 32 + acol;
                float4 v0 = *(const float4*)(ap);
                float4 v1 = *(const float4*)(ap + 4);
                float4 v2 = *(const float4*)(ap + 8);
                float4 v3 = *(const float4*)(ap + 12);
                unsigned short r[16] = {
                    bf16_bits(v0.x), bf16_bits(v0.y), bf16_bits(v0.z), bf16_bits(v0.w),
                    bf16_bits(v1.x), bf16_bits(v1.y), bf16_bits(v1.z), bf16_bits(v1.w),
                    bf16_bits(v2.x), bf16_bits(v2.y), bf16_bits(v2.z), bf16_bits(v2.w),
                    bf16_bits(v3.x), bf16_bits(v3.y), bf16_bits(v3.z), bf16_bits(v3.w)};
                *(uint4*)(sA + arow * 32 + acol) = *(const uint4*)(r);
                *(uint4*)(sA + arow * 32 + acol + 8) = *(const uint4*)(r + 8);
                const float* w0 = Wf + (long)(kt * 32 + 2 * fp) * NDIM + n0 + fc * 8;
                float4 u0 = *(const float4*)(w0);
                float4 u1 = *(const float4*)(w0 + 4);
                float4 u2 = *(const float4*)(w0 + NDIM);
                float4 u3 = *(const float4*)(w0 + NDIM + 4);
                float k0v[8] = {u0.x, u0.y, u0.z, u0.w, u1.x, u1.y, u1.z, u1.w};
                float k1v[8] = {u2.x, u2.y, u2.z, u2.w, u3.x, u3.y, u3.z, u3.w};
#pragma unroll
                for (int i = 0; i < 8; ++i)
                    sB32[(fc * 8 + i) * 16 + fp] =
                        (uint32_t)bf16_bits(k0v[i]) |
                        ((uint32_t)bf16_bits(k1v[i]) << 16);
                __syncthreads();
                compute();
                __syncthreads();
            }
        }
    }

    // epilogue: C/D layout col=lane&15, row=quad*4+reg
    const int crow = m0 + wm + quad * 4;
    if (f32) {
        float* of = (float*)out;
        const float* bf = (const float*)bias;
#pragma unroll
        for (int j = 0; j < 4; ++j) {
            const int col = n0 + wn + j * 16 + lrow;
            const float bv = bf[col];
#pragma unroll
            for (int i = 0; i < 4; ++i) {
                const long rbase = (long)(crow + i * 16) * NDIM + col;
#pragma unroll
                for (int r = 0; r < 4; ++r) {
                    const float x = acc[i][j][r] + bv;
                    of[rbase + (long)r * NDIM] = 1.0f / (1.0f + __expf(-x));
                }
            }
        }
    } else {
        __bf16* ob = (__bf16*)out;
        const __bf16* bb = (const __bf16*)bias;
#pragma unroll
        for (int j = 0; j < 4; ++j) {
            const int col = n0 + wn + j * 16 + lrow;
            const float bv = (float)bb[col];
#pragma unroll
            for (int i = 0; i < 4; ++i) {
                const long rbase = (long)(crow + i * 16) * NDIM + col;
#pragma unroll
                for (int r = 0; r < 4; ++r) {
                    const float x = acc[i][j][r] + bv;
                    ob[rbase + (long)r * NDIM] = (__bf16)(1.0f / (1.0f + __expf(-x)));
                }
            }
        }
    }
}

extern "C" void kernel_launch(void* const* d_in, const int* in_sizes, int n_in,
                              void* d_out, int out_size, void* d_ws,
                              size_t ws_size, hipStream_t stream) {
    const void* X = d_in[0];     // input_data (8192 x 4096)
    const void* W = d_in[1];     // W (4096 x 4096), K x N
    const void* bias = d_in[2];  // hidden_bias (4096)

    const size_t wt_bytes = (size_t)KDIM * NDIM * sizeof(__bf16);  // 33.5 MB
    const size_t xb_bytes = (size_t)MDIM * KDIM * sizeof(__bf16);  // 67 MB

    if (ws_size >= wt_bytes + xb_bytes) {
        __bf16* WT = (__bf16*)d_ws;
        __bf16* Xb = (__bf16*)((char*)d_ws + wt_bytes);
        prep<<<8192 + 4096, 256, 0, stream>>>(X, W, Xb, WT);
        gemm256<<<dim3((MDIM / 256) * (NDIM / 256)), 512, 0, stream>>>(
            X, Xb, WT, bias, d_out);
    } else if (ws_size >= wt_bytes) {
        __bf16* WT = (__bf16*)d_ws;
        transpose_w<<<dim3(NDIM / 64, KDIM / 64), 256, 0, stream>>>(X, W, WT);
        dim3 gg(NDIM / 128, MDIM / 128);
        gemm_bias_sigmoid<1><<<gg, 256, 0, stream>>>(X, nullptr, W, WT, bias, d_out);
    } else {
        dim3 gg(NDIM / 128, MDIM / 128);
        gemm_bias_sigmoid<2><<<gg, 256, 0, stream>>>(X, nullptr, W, nullptr, bias, d_out);
    }
}